// Round 1
// baseline (22485.197 us; speedup 1.0000x reference)
//
#include <hip/hip_runtime.h>
#include <hip/hip_bf16.h>
#include <cstdint>

#define N_NODES 50000
#define M_SRC   1024
#define E_EDGES 200000
#define EMB     256
#define HIDN    512
#define VOCABSZ 512

// ---------------------------------------------------------------- embedding
__global__ void embed_kernel(const int* __restrict__ tgt_x,
                             const float* __restrict__ table,
                             float* __restrict__ h)
{
    int n = blockIdx.x, d = threadIdx.x;
    const int* tx = tgt_x + (size_t)n * 3;
    float s = table[(size_t)tx[0] * EMB + d]
            + table[(size_t)tx[1] * EMB + d]
            + table[(size_t)tx[2] * EMB + d];
    h[(size_t)n * EMB + d] = s;
}

// ---------------------------------------------------------------- generic NN GEMM
// out[n][j] (op)= sum_i A[n][i]*B[i][j]  (+bias[j]) (+add[n][j]) (+=out) (relu)
// BJ = 128 or 256. Block: 64 rows x BJ cols, 256 threads, per-thread 4 x (BJ/64*4).
template<int BJ>
__global__ void gemm_kernel(const float* __restrict__ A, const float* __restrict__ B,
                            float* __restrict__ out, const float* __restrict__ add,
                            const float* __restrict__ bias,
                            int NR, int K, int J, int doAcc, int doRelu)
{
    constexpr int CQ = BJ / 64;          // 4-wide col chunks per thread
    __shared__ float As[64][17];
    __shared__ float Bs[16][BJ];
    const int tid = threadIdx.x;
    const int n0 = blockIdx.x * 64;
    const int j0 = blockIdx.y * BJ;
    const int ty = tid >> 4, tx = tid & 15;

    float acc[4][CQ * 4];
#pragma unroll
    for (int i = 0; i < 4; i++)
#pragma unroll
        for (int j = 0; j < CQ * 4; j++) acc[i][j] = 0.f;

    for (int kt = 0; kt < K; kt += 16) {
#pragma unroll
        for (int m = 0; m < 4; m++) {
            int idx = tid + m * 256;             // 64*16
            int r = idx >> 4, kk = idx & 15;
            int n = n0 + r;
            As[r][kk] = (n < NR) ? A[(size_t)n * K + kt + kk] : 0.f;
        }
#pragma unroll
        for (int m = 0; m < BJ / 16; m++) {
            int idx = tid + m * 256;             // 16*BJ
            int r = idx / BJ, c = idx % BJ;
            Bs[r][c] = B[(size_t)(kt + r) * J + j0 + c];
        }
        __syncthreads();
#pragma unroll
        for (int kk = 0; kk < 16; kk++) {
            float a[4];
#pragma unroll
            for (int i = 0; i < 4; i++) a[i] = As[ty * 4 + i][kk];
#pragma unroll
            for (int q = 0; q < CQ; q++) {
                float4 b4 = *(const float4*)&Bs[kk][q * 64 + tx * 4];
                float bb[4] = { b4.x, b4.y, b4.z, b4.w };
#pragma unroll
                for (int i = 0; i < 4; i++)
#pragma unroll
                    for (int j = 0; j < 4; j++)
                        acc[i][q * 4 + j] += a[i] * bb[j];
            }
        }
        __syncthreads();
    }
#pragma unroll
    for (int i = 0; i < 4; i++) {
        int n = n0 + ty * 4 + i;
        if (n >= NR) continue;
#pragma unroll
        for (int q = 0; q < CQ; q++) {
#pragma unroll
            for (int j = 0; j < 4; j++) {
                int col = j0 + q * 64 + tx * 4 + j;
                float v = acc[i][q * 4 + j];
                if (bias)  v += bias[col];
                if (add)   v += add[(size_t)n * J + col];
                if (doAcc) v += out[(size_t)n * J + col];
                if (doRelu) v = fmaxf(v, 0.f);
                out[(size_t)n * J + col] = v;
            }
        }
    }
}

// ---------------------------------------------------------------- fused attention
// ctx[n] = softmax(h[n]·k^T / 16) @ k  — one-pass (scores are tiny, no max needed)
// Block: 32 rows, loop over 1024 keys in tiles of 32. 256 threads.
__global__ void attn_kernel(const float* __restrict__ h, const float* __restrict__ k,
                            float* __restrict__ C, int NR)
{
    __shared__ float hs[32][260];
    __shared__ float ks[32][260];
    __shared__ float ps[32][32];
    __shared__ float l[32];
    const int tid = threadIdx.x;
    const int n0 = blockIdx.x * 32;
    const int sy = tid >> 4, sx = tid & 15;   // score phase: rows 2sy+, keys 2sx+
    const int rg = tid >> 5, cg = tid & 31;   // ctx phase: rows rg*4+, cols cg*4 + q*128

#pragma unroll
    for (int m = 0; m < 32; m++) {
        int idx = tid + m * 256;
        int r = idx >> 8, c = idx & 255;
        int n = n0 + r;
        hs[r][c] = (n < NR) ? h[(size_t)n * EMB + c] : 0.f;
    }
    if (tid < 32) l[tid] = 0.f;

    float acc[4][8];
#pragma unroll
    for (int i = 0; i < 4; i++)
#pragma unroll
        for (int j = 0; j < 8; j++) acc[i][j] = 0.f;
    __syncthreads();

    for (int j0 = 0; j0 < M_SRC; j0 += 32) {
#pragma unroll
        for (int m = 0; m < 32; m++) {
            int idx = tid + m * 256;
            int r = idx >> 8, c = idx & 255;
            ks[r][c] = k[(size_t)(j0 + r) * EMB + c];
        }
        __syncthreads();

        float s00 = 0.f, s01 = 0.f, s10 = 0.f, s11 = 0.f;
#pragma unroll 8
        for (int i = 0; i < 256; i++) {
            float h0 = hs[sy * 2][i],     h1 = hs[sy * 2 + 1][i];
            float k0 = ks[sx * 2][i],     k1v = ks[sx * 2 + 1][i];
            s00 += h0 * k0; s01 += h0 * k1v;
            s10 += h1 * k0; s11 += h1 * k1v;
        }
        const float SC = 0.0625f;  // 1/sqrt(256)
        ps[sy * 2    ][sx * 2    ] = __expf(s00 * SC);
        ps[sy * 2    ][sx * 2 + 1] = __expf(s01 * SC);
        ps[sy * 2 + 1][sx * 2    ] = __expf(s10 * SC);
        ps[sy * 2 + 1][sx * 2 + 1] = __expf(s11 * SC);
        __syncthreads();

#pragma unroll
        for (int j = 0; j < 32; j++) {
            float p0 = ps[rg * 4 + 0][j], p1 = ps[rg * 4 + 1][j];
            float p2 = ps[rg * 4 + 2][j], p3 = ps[rg * 4 + 3][j];
#pragma unroll
            for (int q = 0; q < 2; q++) {
                float4 kv = *(const float4*)&ks[j][q * 128 + cg * 4];
                float kk4[4] = { kv.x, kv.y, kv.z, kv.w };
#pragma unroll
                for (int c = 0; c < 4; c++) {
                    acc[0][q * 4 + c] += p0 * kk4[c];
                    acc[1][q * 4 + c] += p1 * kk4[c];
                    acc[2][q * 4 + c] += p2 * kk4[c];
                    acc[3][q * 4 + c] += p3 * kk4[c];
                }
            }
        }
        if (cg == 0) {
#pragma unroll
            for (int i = 0; i < 4; i++) {
                float s = 0.f;
#pragma unroll
                for (int j = 0; j < 32; j++) s += ps[rg * 4 + i][j];
                l[rg * 4 + i] += s;
            }
        }
        __syncthreads();
    }

#pragma unroll
    for (int i = 0; i < 4; i++) {
        int n = n0 + rg * 4 + i;
        if (n >= NR) continue;
        float inv = 1.f / l[rg * 4 + i];
#pragma unroll
        for (int q = 0; q < 2; q++) {
            float4 v;
            v.x = acc[i][q * 4 + 0] * inv;
            v.y = acc[i][q * 4 + 1] * inv;
            v.z = acc[i][q * 4 + 2] * inv;
            v.w = acc[i][q * 4 + 3] * inv;
            *(float4*)&C[(size_t)n * EMB + q * 128 + cg * 4] = v;
        }
    }
}

// ---------------------------------------------------------------- per-type scatter
// Bt[tgt] += h[src] for edges of type t
__global__ void scatter_kernel(const int* __restrict__ ei, const int* __restrict__ et,
                               const float* __restrict__ h, float* __restrict__ Bt, int t)
{
    int d = threadIdx.x;
    for (int e = blockIdx.x; e < E_EDGES; e += gridDim.x) {
        if (et[e] != t) continue;
        int s = ei[e];
        int v = ei[E_EDGES + e];
        atomicAdd(&Bt[(size_t)v * EMB + d], h[(size_t)s * EMB + d]);
    }
}

// ---------------------------------------------------------------- node log-softmax (512)
__global__ void lsm512_kernel(const float* __restrict__ logits, float* __restrict__ out)
{
    int n = blockIdx.x, tid = threadIdx.x;
    float v0 = logits[(size_t)n * VOCABSZ + tid];
    float v1 = logits[(size_t)n * VOCABSZ + 256 + tid];
    float m = fmaxf(v0, v1);
#pragma unroll
    for (int off = 32; off; off >>= 1) m = fmaxf(m, __shfl_xor(m, off));
    __shared__ float red[4], red2[4];
    int w = tid >> 6, lane = tid & 63;
    if (lane == 0) red[w] = m;
    __syncthreads();
    m = fmaxf(fmaxf(red[0], red[1]), fmaxf(red[2], red[3]));
    float e = __expf(v0 - m) + __expf(v1 - m);
#pragma unroll
    for (int off = 32; off; off >>= 1) e += __shfl_xor(e, off);
    if (lane == 0) red2[w] = e;
    __syncthreads();
    float lg = m + __logf(red2[0] + red2[1] + red2[2] + red2[3]);
    out[(size_t)n * VOCABSZ + tid] = v0 - lg;
    out[(size_t)n * VOCABSZ + 256 + tid] = v1 - lg;
}

// ---------------------------------------------------------------- edge head
// one wave per edge: z = [h[src],h[tgt]] @ Wg + bg ; log_softmax over 5
__global__ void edge_head_kernel(const int* __restrict__ ei, const float* __restrict__ h,
                                 const float* __restrict__ Wg, const float* __restrict__ bg,
                                 float* __restrict__ out)
{
    int e = blockIdx.x * 4 + (threadIdx.x >> 6);
    int lane = threadIdx.x & 63;
    int s = ei[e], t = ei[E_EDGES + e];
    float a0 = 0, a1 = 0, a2 = 0, a3 = 0, a4 = 0;
#pragma unroll
    for (int m = 0; m < 8; m++) {
        int i = lane + m * 64;  // 0..511, uniform branch per m
        float f = (i < 256) ? h[(size_t)s * EMB + i] : h[(size_t)t * EMB + i - 256];
        const float* wr = &Wg[(size_t)i * 5];
        a0 += f * wr[0]; a1 += f * wr[1]; a2 += f * wr[2]; a3 += f * wr[3]; a4 += f * wr[4];
    }
#pragma unroll
    for (int off = 32; off; off >>= 1) {
        a0 += __shfl_xor(a0, off); a1 += __shfl_xor(a1, off); a2 += __shfl_xor(a2, off);
        a3 += __shfl_xor(a3, off); a4 += __shfl_xor(a4, off);
    }
    if (lane == 0) {
        float z0 = a0 + bg[0], z1 = a1 + bg[1], z2 = a2 + bg[2], z3 = a3 + bg[3], z4 = a4 + bg[4];
        float mm = fmaxf(fmaxf(fmaxf(z0, z1), fmaxf(z2, z3)), z4);
        float ss = __expf(z0 - mm) + __expf(z1 - mm) + __expf(z2 - mm) + __expf(z3 - mm) + __expf(z4 - mm);
        float lg = mm + __logf(ss);
        float* o = &out[(size_t)e * 5];
        o[0] = z0 - lg; o[1] = z1 - lg; o[2] = z2 - lg; o[3] = z3 - lg; o[4] = z4 - lg;
    }
}

// ---------------------------------------------------------------- launch
extern "C" void kernel_launch(void* const* d_in, const int* in_sizes, int n_in,
                              void* d_out, int out_size, void* d_ws, size_t ws_size,
                              hipStream_t stream)
{
    const int*   tgt_x = (const int*)  d_in[0];
    const float* x     = (const float*)d_in[1];
    const int*   ei    = (const int*)  d_in[2];
    const int*   et    = (const int*)  d_in[3];
    const float* table = (const float*)d_in[4];
    const float* Wh1   = (const float*)d_in[5];
    const float* Wrel1 = (const float*)d_in[6];
    const float* Wsrc1 = (const float*)d_in[7];
    const float* Wh3   = (const float*)d_in[8];
    const float* Wrel3 = (const float*)d_in[9];
    const float* Wsrc3 = (const float*)d_in[10];
    const float* Wz    = (const float*)d_in[11];
    const float* bz    = (const float*)d_in[12];
    const float* Wg    = (const float*)d_in[13];
    const float* bg    = (const float*)d_in[14];
    float* out = (float*)d_out;

    float* h  = (float*)d_ws;                       // N*256
    float* C  = h  + (size_t)N_NODES * EMB;         // N*256 (ctx + agg accumulator)
    float* Bt = C  + (size_t)N_NODES * EMB;         // N*256 (per-type bucket)
    float* k1 = Bt + (size_t)N_NODES * EMB;         // 1024*256
    float* k3 = k1 + (size_t)M_SRC * EMB;
    float* logits = C;                              // reuses C..Bt (N*512 floats, contiguous)

    const int gN = (N_NODES + 63) / 64;             // 782

    embed_kernel<<<N_NODES, 256, 0, stream>>>(tgt_x, table, h);

    gemm_kernel<256><<<dim3(M_SRC / 64, 1), 256, 0, stream>>>(x, Wsrc1, k1, nullptr, nullptr,
                                                              M_SRC, HIDN, EMB, 0, 0);
    gemm_kernel<256><<<dim3(M_SRC / 64, 1), 256, 0, stream>>>(x, Wsrc3, k3, nullptr, nullptr,
                                                              M_SRC, HIDN, EMB, 0, 0);

    for (int layer = 0; layer < 3; layer++) {
        const float* kk   = (layer < 2) ? k1    : k3;
        const float* Wrel = (layer < 2) ? Wrel1 : Wrel3;
        const float* Wh   = (layer < 2) ? Wh1   : Wh3;

        // C = ctx
        attn_kernel<<<(N_NODES + 31) / 32, 256, 0, stream>>>(h, kk, C, N_NODES);

        // C += sum_t scatter_t(h) @ Wrel[t]
        for (int t = 0; t < 4; t++) {
            hipMemsetAsync(Bt, 0, (size_t)N_NODES * EMB * sizeof(float), stream);
            scatter_kernel<<<8192, 256, 0, stream>>>(ei, et, h, Bt, t);
            gemm_kernel<256><<<dim3(gN, 1), 256, 0, stream>>>(Bt, Wrel + (size_t)t * EMB * EMB, C,
                                                              nullptr, nullptr, N_NODES, EMB, EMB, 1, 0);
        }
        // h = relu(h @ Wh + C)   (in-place: full-width blocks own their rows)
        gemm_kernel<256><<<dim3(gN, 1), 256, 0, stream>>>(h, Wh, h, C, nullptr,
                                                          N_NODES, EMB, EMB, 0, 1);
    }

    // node head: logits = h @ Wz + bz ; log_softmax -> out
    gemm_kernel<128><<<dim3(gN, 4), 256, 0, stream>>>(h, Wz, logits, nullptr, bz,
                                                      N_NODES, EMB, VOCABSZ, 0, 0);
    lsm512_kernel<<<N_NODES, 256, 0, stream>>>(logits, out);

    // edge head
    edge_head_kernel<<<E_EDGES / 4, 256, 0, stream>>>(ei, h, Wg, bg, out + (size_t)N_NODES * VOCABSZ);
}

// Round 2
// 3217.897 us; speedup vs baseline: 6.9875x; 6.9875x over previous
//
#include <hip/hip_runtime.h>
#include <hip/hip_bf16.h>
#include <cstdint>

#define N_NODES 50000
#define M_SRC   1024
#define E_EDGES 200000
#define EMB     256
#define HIDN    512
#define VOCABSZ 512

typedef __attribute__((ext_vector_type(8))) short bf16x8;
typedef __attribute__((ext_vector_type(4))) float f32x4;

__device__ inline short f2b(float f) {
    __hip_bfloat16 b = __float2bfloat16(f);
    return *reinterpret_cast<short*>(&b);
}
__device__ inline float b2f(short s) {
    __hip_bfloat16 b = *reinterpret_cast<__hip_bfloat16*>(&s);
    return __bfloat162float(b);
}

// ---------------------------------------------------------------- embedding -> bf16
__global__ void embed_kernel(const int* __restrict__ tgt_x,
                             const float* __restrict__ table,
                             short* __restrict__ h)
{
    int n = blockIdx.x, d = threadIdx.x;
    const int* tx = tgt_x + (size_t)n * 3;
    float s = table[(size_t)tx[0] * EMB + d]
            + table[(size_t)tx[1] * EMB + d]
            + table[(size_t)tx[2] * EMB + d];
    h[(size_t)n * EMB + d] = f2b(s);
}

// ---------------------------------------------------------------- fp32 -> bf16 flat convert
__global__ void convert_kernel(const float* __restrict__ in, short* __restrict__ out, int n)
{
    int i = blockIdx.x * 256 + threadIdx.x;
    if (i * 4 < n) {
        float4 v = *(const float4*)&in[i * 4];
        short4 o;
        o.x = f2b(v.x); o.y = f2b(v.y); o.z = f2b(v.z); o.w = f2b(v.w);
        *(short4*)&out[i * 4] = o;
    }
}

// ---------------------------------------------------------------- transpose to bf16
// in [R][C] (fp32 or bf16) -> out [C][R] bf16.  R, C multiples of 32.
template<typename TIN>
__global__ void transpose_kernel(const TIN* __restrict__ in, short* __restrict__ out, int R, int C)
{
    __shared__ float t[32][33];
    int tx = threadIdx.x & 31, ty = threadIdx.x >> 5;   // 32 x 8
    int r0 = blockIdx.y * 32, c0 = blockIdx.x * 32;
#pragma unroll
    for (int i = 0; i < 4; i++) {
        int r = ty + i * 8;
        TIN v = in[(size_t)(r0 + r) * C + c0 + tx];
        if constexpr (sizeof(TIN) == 4) t[r][tx] = v;
        else                            t[r][tx] = b2f(v);
    }
    __syncthreads();
#pragma unroll
    for (int i = 0; i < 4; i++) {
        int r = ty + i * 8;
        out[(size_t)(c0 + r) * R + r0 + tx] = f2b(t[tx][r]);
    }
}

// ---------------------------------------------------------------- MFMA GEMM
// out[n][j] = op( sum_k A[n][k] * BT[j][k] )
// A: bf16 [NR][K] row-major.  BT: bf16 [J][K] row-major (i.e. B transposed).
// 128x128 tile, 4 waves (2x2 of 64x64), BK=32, mfma_f32_16x16x32_bf16.
// MODE 0: store bf16(acc)
// MODE 1: store bf16(exp(acc/16))            (attention scores -> P)
// MODE 2: store f32 (acc * aux[n])           (ctx, aux = 1/rowsum)
// MODE 3: store bf16(relu(acc + aux[n*J+j])) (layer update, aux = C)
// MODE 4: store f32 (acc + bias[j])          (node head logits)
template<int MODE>
__global__ __launch_bounds__(256) void mgemm(
    const short* __restrict__ A, const short* __restrict__ BT,
    void* __restrict__ outp, const float* __restrict__ aux,
    const float* __restrict__ bias, int NR, int K, int J)
{
    __shared__ short As[128 * 40];   // stride 40 bf16 (80 B) kills b128 bank conflicts
    __shared__ short Bs[128 * 40];
    const int tid  = threadIdx.x;
    const int n0   = blockIdx.x * 128;
    const int j0   = blockIdx.y * 128;
    const int lane = tid & 63, wid = tid >> 6;
    const int wr   = wid >> 1, wc = wid & 1;

    f32x4 acc[4][4];
#pragma unroll
    for (int m = 0; m < 4; m++)
#pragma unroll
        for (int n = 0; n < 4; n++) acc[m][n] = (f32x4){0.f, 0.f, 0.f, 0.f};

    for (int kt = 0; kt < K; kt += 32) {
#pragma unroll
        for (int r = 0; r < 2; r++) {
            int idx = tid + r * 256;            // 512 chunks of 8 bf16
            int row = idx >> 2, ko = (idx & 3) * 8;
            int n = n0 + row;
            bf16x8 av = {0, 0, 0, 0, 0, 0, 0, 0};
            if (n < NR) av = *(const bf16x8*)&A[(size_t)n * K + kt + ko];
            *(bf16x8*)&As[row * 40 + ko] = av;
            *(bf16x8*)&Bs[row * 40 + ko] = *(const bf16x8*)&BT[(size_t)(j0 + row) * K + kt + ko];
        }
        __syncthreads();
        bf16x8 af[4], bfr[4];
#pragma unroll
        for (int m = 0; m < 4; m++)
            af[m] = *(const bf16x8*)&As[(wr * 64 + m * 16 + (lane & 15)) * 40 + (lane >> 4) * 8];
#pragma unroll
        for (int n = 0; n < 4; n++)
            bfr[n] = *(const bf16x8*)&Bs[(wc * 64 + n * 16 + (lane & 15)) * 40 + (lane >> 4) * 8];
#pragma unroll
        for (int m = 0; m < 4; m++)
#pragma unroll
            for (int n = 0; n < 4; n++)
                acc[m][n] = __builtin_amdgcn_mfma_f32_16x16x32_bf16(af[m], bfr[n], acc[m][n], 0, 0, 0);
        __syncthreads();
    }

#pragma unroll
    for (int m = 0; m < 4; m++) {
        int rbase = wr * 64 + m * 16 + ((lane >> 4) * 4);
#pragma unroll
        for (int r = 0; r < 4; r++) {
            int n_g = n0 + rbase + r;
            if (n_g >= NR) continue;
#pragma unroll
            for (int nn = 0; nn < 4; nn++) {
                int j_g = j0 + wc * 64 + nn * 16 + (lane & 15);
                float v = acc[m][nn][r];
                if constexpr (MODE == 0) {
                    ((short*)outp)[(size_t)n_g * J + j_g] = f2b(v);
                } else if constexpr (MODE == 1) {
                    ((short*)outp)[(size_t)n_g * J + j_g] = f2b(__expf(v * 0.0625f));
                } else if constexpr (MODE == 2) {
                    ((float*)outp)[(size_t)n_g * J + j_g] = v * aux[n_g];
                } else if constexpr (MODE == 3) {
                    float a = aux[(size_t)n_g * J + j_g];
                    ((short*)outp)[(size_t)n_g * J + j_g] = f2b(fmaxf(v + a, 0.f));
                } else {
                    ((float*)outp)[(size_t)n_g * J + j_g] = v + bias[j_g];
                }
            }
        }
    }
}

// ---------------------------------------------------------------- row-sum of P -> 1/sum
__global__ void rowsum_kernel(const short* __restrict__ P, float* __restrict__ inv)
{
    int n = blockIdx.x, tid = threadIdx.x;
    short4 v = *(const short4*)&P[(size_t)n * 1024 + tid * 4];
    float s = b2f(v.x) + b2f(v.y) + b2f(v.z) + b2f(v.w);
#pragma unroll
    for (int off = 32; off; off >>= 1) s += __shfl_xor(s, off);
    __shared__ float red[4];
    int w = tid >> 6, lane = tid & 63;
    if (lane == 0) red[w] = s;
    __syncthreads();
    if (tid == 0) inv[n] = 1.f / (red[0] + red[1] + red[2] + red[3]);
}

// ---------------------------------------------------------------- edge scatter
// C[tgt] += G[et][src]   (G: bf16 [4][N][256], one wave per edge)
__global__ void scatter_kernel(const int* __restrict__ ei, const int* __restrict__ et,
                               const short* __restrict__ G, float* __restrict__ C)
{
    int w    = (blockIdx.x * 256 + threadIdx.x) >> 6;
    int lane = threadIdx.x & 63;
    int nw   = (gridDim.x * 256) >> 6;
    for (int e = w; e < E_EDGES; e += nw) {
        int s = ei[e], tg = ei[E_EDGES + e], t = et[e];
        short4 g = *(const short4*)&G[((size_t)t * N_NODES + s) * EMB + lane * 4];
        float* c = &C[(size_t)tg * EMB + lane * 4];
        atomicAdd(c + 0, b2f(g.x));
        atomicAdd(c + 1, b2f(g.y));
        atomicAdd(c + 2, b2f(g.z));
        atomicAdd(c + 3, b2f(g.w));
    }
}

// ---------------------------------------------------------------- node log-softmax (512)
__global__ void lsm512_kernel(const float* __restrict__ logits, float* __restrict__ out)
{
    int n = blockIdx.x, tid = threadIdx.x;
    float v0 = logits[(size_t)n * VOCABSZ + tid];
    float v1 = logits[(size_t)n * VOCABSZ + 256 + tid];
    float m = fmaxf(v0, v1);
#pragma unroll
    for (int off = 32; off; off >>= 1) m = fmaxf(m, __shfl_xor(m, off));
    __shared__ float red[4], red2[4];
    int w = tid >> 6, lane = tid & 63;
    if (lane == 0) red[w] = m;
    __syncthreads();
    m = fmaxf(fmaxf(red[0], red[1]), fmaxf(red[2], red[3]));
    float e = __expf(v0 - m) + __expf(v1 - m);
#pragma unroll
    for (int off = 32; off; off >>= 1) e += __shfl_xor(e, off);
    if (lane == 0) red2[w] = e;
    __syncthreads();
    float lg = m + __logf(red2[0] + red2[1] + red2[2] + red2[3]);
    out[(size_t)n * VOCABSZ + tid] = v0 - lg;
    out[(size_t)n * VOCABSZ + 256 + tid] = v1 - lg;
}

// ---------------------------------------------------------------- edge head
__global__ void edge_head_kernel(const int* __restrict__ ei, const short* __restrict__ h,
                                 const float* __restrict__ Wg, const float* __restrict__ bg,
                                 float* __restrict__ out)
{
    int e = blockIdx.x * 4 + (threadIdx.x >> 6);
    int lane = threadIdx.x & 63;
    int s = ei[e], t = ei[E_EDGES + e];
    float a0 = 0, a1 = 0, a2 = 0, a3 = 0, a4 = 0;
#pragma unroll
    for (int m = 0; m < 8; m++) {
        int i = lane + m * 64;
        float f = (i < 256) ? b2f(h[(size_t)s * EMB + i]) : b2f(h[(size_t)t * EMB + i - 256]);
        const float* wr = &Wg[(size_t)i * 5];
        a0 += f * wr[0]; a1 += f * wr[1]; a2 += f * wr[2]; a3 += f * wr[3]; a4 += f * wr[4];
    }
#pragma unroll
    for (int off = 32; off; off >>= 1) {
        a0 += __shfl_xor(a0, off); a1 += __shfl_xor(a1, off); a2 += __shfl_xor(a2, off);
        a3 += __shfl_xor(a3, off); a4 += __shfl_xor(a4, off);
    }
    if (lane == 0) {
        float z0 = a0 + bg[0], z1 = a1 + bg[1], z2 = a2 + bg[2], z3 = a3 + bg[3], z4 = a4 + bg[4];
        float mm = fmaxf(fmaxf(fmaxf(z0, z1), fmaxf(z2, z3)), z4);
        float ss = __expf(z0 - mm) + __expf(z1 - mm) + __expf(z2 - mm) + __expf(z3 - mm) + __expf(z4 - mm);
        float lg = mm + __logf(ss);
        float* o = &out[(size_t)e * 5];
        o[0] = z0 - lg; o[1] = z1 - lg; o[2] = z2 - lg; o[3] = z3 - lg; o[4] = z4 - lg;
    }
}

// ---------------------------------------------------------------- launch
extern "C" void kernel_launch(void* const* d_in, const int* in_sizes, int n_in,
                              void* d_out, int out_size, void* d_ws, size_t ws_size,
                              hipStream_t stream)
{
    const int*   tgt_x = (const int*)  d_in[0];
    const float* x     = (const float*)d_in[1];
    const int*   ei    = (const int*)  d_in[2];
    const int*   et    = (const int*)  d_in[3];
    const float* table = (const float*)d_in[4];
    const float* Wh1   = (const float*)d_in[5];
    const float* Wrel1 = (const float*)d_in[6];
    const float* Wsrc1 = (const float*)d_in[7];
    const float* Wh3   = (const float*)d_in[8];
    const float* Wrel3 = (const float*)d_in[9];
    const float* Wsrc3 = (const float*)d_in[10];
    const float* Wz    = (const float*)d_in[11];
    const float* bz    = (const float*)d_in[12];
    const float* Wg    = (const float*)d_in[13];
    const float* bg    = (const float*)d_in[14];
    float* out = (float*)d_out;

    // ---- workspace layout (~210 MB)
    short* h_a = (short*)d_ws;                              // N*256 bf16
    short* h_b = h_a + (size_t)N_NODES * EMB;               // N*256 bf16
    float* C   = (float*)(h_b + (size_t)N_NODES * EMB);     // N*256 f32
    short* PG  = (short*)(C + (size_t)N_NODES * EMB);       // N*1024 bf16 (P | G[4] | logits f32)
    float* inv = (float*)(PG + (size_t)N_NODES * 1024);     // N f32
    short* k1b = (short*)(inv + N_NODES);                   // [1024][256]
    short* k3b = k1b + M_SRC * EMB;
    short* k1T = k3b + M_SRC * EMB;                         // [256][1024]
    short* k3T = k1T + M_SRC * EMB;
    short* x_b = k3T + M_SRC * EMB;                         // [1024][512]
    short* WsT1 = x_b + M_SRC * HIDN;                       // [256][512]
    short* WsT3 = WsT1 + EMB * HIDN;
    short* WhT1 = WsT3 + EMB * HIDN;                        // [256][256]
    short* WhT3 = WhT1 + EMB * EMB;
    short* WrT1 = WhT3 + EMB * EMB;                         // 4 x [256][256]
    short* WrT3 = WrT1 + 4 * EMB * EMB;
    short* WzT  = WrT3 + 4 * EMB * EMB;                     // [512][256]
    float* logits = (float*)PG;                             // N*512 f32 (reuses P/G)

    const int gN = (N_NODES + 127) / 128;                   // 391

    // ---- weight prep (tiny)
    convert_kernel<<<(M_SRC * HIDN / 4 + 255) / 256, 256, 0, stream>>>(x, x_b, M_SRC * HIDN);
    transpose_kernel<float><<<dim3(EMB / 32, HIDN / 32), 256, 0, stream>>>(Wsrc1, WsT1, HIDN, EMB);
    transpose_kernel<float><<<dim3(EMB / 32, HIDN / 32), 256, 0, stream>>>(Wsrc3, WsT3, HIDN, EMB);
    transpose_kernel<float><<<dim3(EMB / 32, EMB / 32), 256, 0, stream>>>(Wh1, WhT1, EMB, EMB);
    transpose_kernel<float><<<dim3(EMB / 32, EMB / 32), 256, 0, stream>>>(Wh3, WhT3, EMB, EMB);
    for (int t = 0; t < 4; t++) {
        transpose_kernel<float><<<dim3(EMB / 32, EMB / 32), 256, 0, stream>>>(
            Wrel1 + (size_t)t * EMB * EMB, WrT1 + (size_t)t * EMB * EMB, EMB, EMB);
        transpose_kernel<float><<<dim3(EMB / 32, EMB / 32), 256, 0, stream>>>(
            Wrel3 + (size_t)t * EMB * EMB, WrT3 + (size_t)t * EMB * EMB, EMB, EMB);
    }
    transpose_kernel<float><<<dim3(VOCABSZ / 32, EMB / 32), 256, 0, stream>>>(Wz, WzT, EMB, VOCABSZ);

    // ---- k = x @ Wsrc  (bf16), and kT
    mgemm<0><<<dim3(M_SRC / 128, EMB / 128), 256, 0, stream>>>(x_b, WsT1, k1b, nullptr, nullptr, M_SRC, HIDN, EMB);
    mgemm<0><<<dim3(M_SRC / 128, EMB / 128), 256, 0, stream>>>(x_b, WsT3, k3b, nullptr, nullptr, M_SRC, HIDN, EMB);
    transpose_kernel<short><<<dim3(EMB / 32, M_SRC / 32), 256, 0, stream>>>(k1b, k1T, M_SRC, EMB);
    transpose_kernel<short><<<dim3(EMB / 32, M_SRC / 32), 256, 0, stream>>>(k3b, k3T, M_SRC, EMB);

    // ---- embedding
    embed_kernel<<<N_NODES, 256, 0, stream>>>(tgt_x, table, h_a);

    short* h_cur = h_a;
    short* h_nxt = h_b;
    for (int layer = 0; layer < 3; layer++) {
        const short* kb   = (layer < 2) ? k1b  : k3b;
        const short* kT   = (layer < 2) ? k1T  : k3T;
        const short* WrT  = (layer < 2) ? WrT1 : WrT3;
        const short* WhT  = (layer < 2) ? WhT1 : WhT3;

        // P = exp(h @ k^T / 16)   [N,1024] bf16
        mgemm<1><<<dim3(gN, M_SRC / 128), 256, 0, stream>>>(h_cur, kb, PG, nullptr, nullptr,
                                                            N_NODES, EMB, M_SRC);
        rowsum_kernel<<<N_NODES, 256, 0, stream>>>(PG, inv);
        // C = (P @ k) * inv
        mgemm<2><<<dim3(gN, EMB / 128), 256, 0, stream>>>(PG, kT, C, inv, nullptr,
                                                          N_NODES, M_SRC, EMB);
        // G_t = h @ Wrel[t]  (bf16, into PG region — P is dead now)
        for (int t = 0; t < 4; t++)
            mgemm<0><<<dim3(gN, EMB / 128), 256, 0, stream>>>(h_cur, WrT + (size_t)t * EMB * EMB,
                                                              PG + (size_t)t * N_NODES * EMB,
                                                              nullptr, nullptr, N_NODES, EMB, EMB);
        // C += G[et][src] at tgt
        scatter_kernel<<<2048, 256, 0, stream>>>(ei, et, PG, C);
        // h_nxt = relu(h @ Wh + C)
        mgemm<3><<<dim3(gN, EMB / 128), 256, 0, stream>>>(h_cur, WhT, h_nxt, C, nullptr,
                                                          N_NODES, EMB, EMB);
        short* tmp = h_cur; h_cur = h_nxt; h_nxt = tmp;
    }

    // ---- node head
    mgemm<4><<<dim3(gN, VOCABSZ / 128), 256, 0, stream>>>(h_cur, WzT, logits, nullptr, bz,
                                                          N_NODES, EMB, VOCABSZ);
    lsm512_kernel<<<N_NODES, 256, 0, stream>>>(logits, out);

    // ---- edge head
    edge_head_kernel<<<E_EDGES / 4, 256, 0, stream>>>(ei, h_cur, Wg, bg, out + (size_t)N_NODES * VOCABSZ);
}

// Round 3
// 1232.982 us; speedup vs baseline: 18.2364x; 2.6098x over previous
//
#include <hip/hip_runtime.h>
#include <hip/hip_bf16.h>
#include <cstdint>

#define N_NODES 50000
#define M_SRC   1024
#define E_EDGES 200000
#define EMB     256
#define HIDN    512
#define VOCABSZ 512

typedef __attribute__((ext_vector_type(8))) short bf16x8;
typedef __attribute__((ext_vector_type(4))) float f32x4;

__device__ inline short f2b(float f) {
    __hip_bfloat16 b = __float2bfloat16(f);
    return *reinterpret_cast<short*>(&b);
}
__device__ inline float b2f(short s) {
    __hip_bfloat16 b = *reinterpret_cast<__hip_bfloat16*>(&s);
    return __bfloat162float(b);
}

// ---------------------------------------------------------------- embedding -> bf16
__global__ void embed_kernel(const int* __restrict__ tgt_x,
                             const float* __restrict__ table,
                             short* __restrict__ h)
{
    int n = blockIdx.x, d = threadIdx.x;
    const int* tx = tgt_x + (size_t)n * 3;
    float s = table[(size_t)tx[0] * EMB + d]
            + table[(size_t)tx[1] * EMB + d]
            + table[(size_t)tx[2] * EMB + d];
    h[(size_t)n * EMB + d] = f2b(s);
}

// ---------------------------------------------------------------- fp32 -> bf16 flat convert
__global__ void convert_kernel(const float* __restrict__ in, short* __restrict__ out, int n)
{
    int i = blockIdx.x * 256 + threadIdx.x;
    if (i * 4 < n) {
        float4 v = *(const float4*)&in[i * 4];
        short4 o;
        o.x = f2b(v.x); o.y = f2b(v.y); o.z = f2b(v.z); o.w = f2b(v.w);
        *(short4*)&out[i * 4] = o;
    }
}

// ---------------------------------------------------------------- transpose to bf16
template<typename TIN>
__global__ void transpose_kernel(const TIN* __restrict__ in, short* __restrict__ out, int R, int C)
{
    __shared__ float t[32][33];
    int tx = threadIdx.x & 31, ty = threadIdx.x >> 5;   // 32 x 8
    int r0 = blockIdx.y * 32, c0 = blockIdx.x * 32;
#pragma unroll
    for (int i = 0; i < 4; i++) {
        int r = ty + i * 8;
        TIN v = in[(size_t)(r0 + r) * C + c0 + tx];
        if constexpr (sizeof(TIN) == 4) t[r][tx] = v;
        else                            t[r][tx] = b2f(v);
    }
    __syncthreads();
#pragma unroll
    for (int i = 0; i < 4; i++) {
        int r = ty + i * 8;
        out[(size_t)(c0 + r) * R + r0 + tx] = f2b(t[tx][r]);
    }
}

// ---------------------------------------------------------------- MFMA GEMM
// out[n][j] = op( sum_k A[n][k] * BT[j][k] )
// MODE 0: bf16(acc)   MODE 1: bf16(exp(acc/16))   MODE 2: f32 acc*aux[n]
// MODE 3: bf16(relu(acc+aux[n*J+j]))              MODE 4: f32 acc+bias[j]
template<int MODE>
__global__ __launch_bounds__(256) void mgemm(
    const short* __restrict__ A, const short* __restrict__ BT,
    void* __restrict__ outp, const float* __restrict__ aux,
    const float* __restrict__ bias, int NR, int K, int J)
{
    __shared__ short As[128 * 40];
    __shared__ short Bs[128 * 40];
    const int tid  = threadIdx.x;
    const int n0   = blockIdx.x * 128;
    const int j0   = blockIdx.y * 128;
    const int lane = tid & 63, wid = tid >> 6;
    const int wr   = wid >> 1, wc = wid & 1;

    f32x4 acc[4][4];
#pragma unroll
    for (int m = 0; m < 4; m++)
#pragma unroll
        for (int n = 0; n < 4; n++) acc[m][n] = (f32x4){0.f, 0.f, 0.f, 0.f};

    for (int kt = 0; kt < K; kt += 32) {
#pragma unroll
        for (int r = 0; r < 2; r++) {
            int idx = tid + r * 256;
            int row = idx >> 2, ko = (idx & 3) * 8;
            int n = n0 + row;
            bf16x8 av = {0, 0, 0, 0, 0, 0, 0, 0};
            if (n < NR) av = *(const bf16x8*)&A[(size_t)n * K + kt + ko];
            *(bf16x8*)&As[row * 40 + ko] = av;
            *(bf16x8*)&Bs[row * 40 + ko] = *(const bf16x8*)&BT[(size_t)(j0 + row) * K + kt + ko];
        }
        __syncthreads();
        bf16x8 af[4], bfr[4];
#pragma unroll
        for (int m = 0; m < 4; m++)
            af[m] = *(const bf16x8*)&As[(wr * 64 + m * 16 + (lane & 15)) * 40 + (lane >> 4) * 8];
#pragma unroll
        for (int n = 0; n < 4; n++)
            bfr[n] = *(const bf16x8*)&Bs[(wc * 64 + n * 16 + (lane & 15)) * 40 + (lane >> 4) * 8];
#pragma unroll
        for (int m = 0; m < 4; m++)
#pragma unroll
            for (int n = 0; n < 4; n++)
                acc[m][n] = __builtin_amdgcn_mfma_f32_16x16x32_bf16(af[m], bfr[n], acc[m][n], 0, 0, 0);
        __syncthreads();
    }

#pragma unroll
    for (int m = 0; m < 4; m++) {
        int rbase = wr * 64 + m * 16 + ((lane >> 4) * 4);
#pragma unroll
        for (int r = 0; r < 4; r++) {
            int n_g = n0 + rbase + r;
            if (n_g >= NR) continue;
#pragma unroll
            for (int nn = 0; nn < 4; nn++) {
                int j_g = j0 + wc * 64 + nn * 16 + (lane & 15);
                float v = acc[m][nn][r];
                if constexpr (MODE == 0) {
                    ((short*)outp)[(size_t)n_g * J + j_g] = f2b(v);
                } else if constexpr (MODE == 1) {
                    ((short*)outp)[(size_t)n_g * J + j_g] = f2b(__expf(v * 0.0625f));
                } else if constexpr (MODE == 2) {
                    ((float*)outp)[(size_t)n_g * J + j_g] = v * aux[n_g];
                } else if constexpr (MODE == 3) {
                    float a = aux[(size_t)n_g * J + j_g];
                    ((short*)outp)[(size_t)n_g * J + j_g] = f2b(fmaxf(v + a, 0.f));
                } else {
                    ((float*)outp)[(size_t)n_g * J + j_g] = v + bias[j_g];
                }
            }
        }
    }
}

// ---------------------------------------------------------------- row-sum of P -> 1/sum
__global__ void rowsum_kernel(const short* __restrict__ P, float* __restrict__ inv)
{
    int n = blockIdx.x, tid = threadIdx.x;
    short4 v = *(const short4*)&P[(size_t)n * 1024 + tid * 4];
    float s = b2f(v.x) + b2f(v.y) + b2f(v.z) + b2f(v.w);
#pragma unroll
    for (int off = 32; off; off >>= 1) s += __shfl_xor(s, off);
    __shared__ float red[4];
    int w = tid >> 6, lane = tid & 63;
    if (lane == 0) red[w] = s;
    __syncthreads();
    if (tid == 0) inv[n] = 1.f / (red[0] + red[1] + red[2] + red[3]);
}

// ---------------------------------------------------------------- CSR build (once per call)
__global__ void hist_kernel(const int* __restrict__ ei, int* __restrict__ deg)
{
    int e = blockIdx.x * 256 + threadIdx.x;
    if (e < E_EDGES) atomicAdd(&deg[ei[E_EDGES + e]], 1);
}

__global__ void scan1_kernel(const int* __restrict__ deg, int* __restrict__ incl,
                             int* __restrict__ bsum)
{
    __shared__ int s[256];
    int i = blockIdx.x * 256 + threadIdx.x;
    int v = (i < N_NODES) ? deg[i] : 0;
    s[threadIdx.x] = v;
    __syncthreads();
#pragma unroll
    for (int off = 1; off < 256; off <<= 1) {
        int t = (threadIdx.x >= off) ? s[threadIdx.x - off] : 0;
        __syncthreads();
        s[threadIdx.x] += t;
        __syncthreads();
    }
    if (i < N_NODES) incl[i] = s[threadIdx.x];
    if (threadIdx.x == 255) bsum[blockIdx.x] = s[255];
}

__global__ void scan2_kernel(int* __restrict__ bsum, int nb)
{
    __shared__ int s[256];
    int v = (threadIdx.x < nb) ? bsum[threadIdx.x] : 0;
    s[threadIdx.x] = v;
    __syncthreads();
#pragma unroll
    for (int off = 1; off < 256; off <<= 1) {
        int t = (threadIdx.x >= off) ? s[threadIdx.x - off] : 0;
        __syncthreads();
        s[threadIdx.x] += t;
        __syncthreads();
    }
    if (threadIdx.x < nb) bsum[threadIdx.x] = s[threadIdx.x];
}

__global__ void scan3_kernel(const int* __restrict__ deg, const int* __restrict__ incl,
                             const int* __restrict__ bsum, int* __restrict__ row_ptr,
                             int* __restrict__ cursor)
{
    int i = blockIdx.x * 256 + threadIdx.x;
    if (i >= N_NODES) return;
    int pref = (blockIdx.x > 0) ? bsum[blockIdx.x - 1] : 0;
    int start = pref + incl[i] - deg[i];
    row_ptr[i] = start;
    cursor[i]  = start;
    if (i == N_NODES - 1) row_ptr[N_NODES] = pref + incl[i];
}

__global__ void fill_kernel(const int* __restrict__ ei, const int* __restrict__ et,
                            int* __restrict__ cursor, int* __restrict__ eidx)
{
    int e = blockIdx.x * 256 + threadIdx.x;
    if (e >= E_EDGES) return;
    int tg = ei[E_EDGES + e];
    int slot = atomicAdd(&cursor[tg], 1);
    eidx[slot] = ei[e] | (et[e] << 16);   // src < 65536, type < 4
}

// ---------------------------------------------------------------- CSR gather-aggregate
// C[tgt] += sum_{e in csr(tgt)} G[src_e][type_e*256 + d]    (one wave per target)
__global__ void agg_kernel(const int* __restrict__ row_ptr, const int* __restrict__ eidx,
                           const short* __restrict__ G, float* __restrict__ C)
{
    int w = (blockIdx.x * 256 + threadIdx.x) >> 6;
    if (w >= N_NODES) return;
    int lane = threadIdx.x & 63;
    int s0 = row_ptr[w], s1 = row_ptr[w + 1];
    float a0 = 0.f, a1 = 0.f, a2 = 0.f, a3 = 0.f;
    for (int i = s0; i < s1; i++) {
        int p = eidx[i];
        int s = p & 0xFFFF, t = p >> 16;
        short4 g = *(const short4*)&G[(size_t)s * 1024 + t * 256 + lane * 4];
        a0 += b2f(g.x); a1 += b2f(g.y); a2 += b2f(g.z); a3 += b2f(g.w);
    }
    float4 c = *(float4*)&C[(size_t)w * EMB + lane * 4];
    c.x += a0; c.y += a1; c.z += a2; c.w += a3;
    *(float4*)&C[(size_t)w * EMB + lane * 4] = c;
}

// ---------------------------------------------------------------- node log-softmax (512)
__global__ void lsm512_kernel(const float* __restrict__ logits, float* __restrict__ out)
{
    int n = blockIdx.x, tid = threadIdx.x;
    float v0 = logits[(size_t)n * VOCABSZ + tid];
    float v1 = logits[(size_t)n * VOCABSZ + 256 + tid];
    float m = fmaxf(v0, v1);
#pragma unroll
    for (int off = 32; off; off >>= 1) m = fmaxf(m, __shfl_xor(m, off));
    __shared__ float red[4], red2[4];
    int w = tid >> 6, lane = tid & 63;
    if (lane == 0) red[w] = m;
    __syncthreads();
    m = fmaxf(fmaxf(red[0], red[1]), fmaxf(red[2], red[3]));
    float e = __expf(v0 - m) + __expf(v1 - m);
#pragma unroll
    for (int off = 32; off; off >>= 1) e += __shfl_xor(e, off);
    if (lane == 0) red2[w] = e;
    __syncthreads();
    float lg = m + __logf(red2[0] + red2[1] + red2[2] + red2[3]);
    out[(size_t)n * VOCABSZ + tid] = v0 - lg;
    out[(size_t)n * VOCABSZ + 256 + tid] = v1 - lg;
}

// ---------------------------------------------------------------- edge head
__global__ void edge_head_kernel(const int* __restrict__ ei, const short* __restrict__ h,
                                 const float* __restrict__ Wg, const float* __restrict__ bg,
                                 float* __restrict__ out)
{
    int e = blockIdx.x * 4 + (threadIdx.x >> 6);
    int lane = threadIdx.x & 63;
    int s = ei[e], t = ei[E_EDGES + e];
    float a0 = 0, a1 = 0, a2 = 0, a3 = 0, a4 = 0;
#pragma unroll
    for (int m = 0; m < 8; m++) {
        int i = lane + m * 64;
        float f = (i < 256) ? b2f(h[(size_t)s * EMB + i]) : b2f(h[(size_t)t * EMB + i - 256]);
        const float* wr = &Wg[(size_t)i * 5];
        a0 += f * wr[0]; a1 += f * wr[1]; a2 += f * wr[2]; a3 += f * wr[3]; a4 += f * wr[4];
    }
#pragma unroll
    for (int off = 32; off; off >>= 1) {
        a0 += __shfl_xor(a0, off); a1 += __shfl_xor(a1, off); a2 += __shfl_xor(a2, off);
        a3 += __shfl_xor(a3, off); a4 += __shfl_xor(a4, off);
    }
    if (lane == 0) {
        float z0 = a0 + bg[0], z1 = a1 + bg[1], z2 = a2 + bg[2], z3 = a3 + bg[3], z4 = a4 + bg[4];
        float mm = fmaxf(fmaxf(fmaxf(z0, z1), fmaxf(z2, z3)), z4);
        float ss = __expf(z0 - mm) + __expf(z1 - mm) + __expf(z2 - mm) + __expf(z3 - mm) + __expf(z4 - mm);
        float lg = mm + __logf(ss);
        float* o = &out[(size_t)e * 5];
        o[0] = z0 - lg; o[1] = z1 - lg; o[2] = z2 - lg; o[3] = z3 - lg; o[4] = z4 - lg;
    }
}

// ---------------------------------------------------------------- launch
extern "C" void kernel_launch(void* const* d_in, const int* in_sizes, int n_in,
                              void* d_out, int out_size, void* d_ws, size_t ws_size,
                              hipStream_t stream)
{
    const int*   tgt_x = (const int*)  d_in[0];
    const float* x     = (const float*)d_in[1];
    const int*   ei    = (const int*)  d_in[2];
    const int*   et    = (const int*)  d_in[3];
    const float* table = (const float*)d_in[4];
    const float* Wh1   = (const float*)d_in[5];
    const float* Wrel1 = (const float*)d_in[6];
    const float* Wsrc1 = (const float*)d_in[7];
    const float* Wh3   = (const float*)d_in[8];
    const float* Wrel3 = (const float*)d_in[9];
    const float* Wsrc3 = (const float*)d_in[10];
    const float* Wz    = (const float*)d_in[11];
    const float* bz    = (const float*)d_in[12];
    const float* Wg    = (const float*)d_in[13];
    const float* bg    = (const float*)d_in[14];
    float* out = (float*)d_out;

    // ---- workspace layout
    short* h_a = (short*)d_ws;                              // N*256 bf16
    short* h_b = h_a + (size_t)N_NODES * EMB;
    float* C   = (float*)(h_b + (size_t)N_NODES * EMB);     // N*256 f32
    short* PG  = (short*)(C + (size_t)N_NODES * EMB);       // N*1024 bf16 (P, then G)
    float* inv = (float*)(PG + (size_t)N_NODES * 1024);     // N f32
    short* k1b = (short*)(inv + N_NODES);                   // [1024][256]
    short* k3b = k1b + M_SRC * EMB;
    short* k1T = k3b + M_SRC * EMB;                         // [256][1024]
    short* k3T = k1T + M_SRC * EMB;
    short* x_b = k3T + M_SRC * EMB;                         // [1024][512]
    short* WsT1 = x_b + M_SRC * HIDN;                       // [256][512]
    short* WsT3 = WsT1 + EMB * HIDN;
    short* WhT1 = WsT3 + EMB * HIDN;                        // [256][256]
    short* WhT3 = WhT1 + EMB * EMB;
    short* WrT1 = WhT3 + EMB * EMB;                         // 4 x [256][256] = [1024][256]
    short* WrT3 = WrT1 + 4 * EMB * EMB;
    short* WzT  = WrT3 + 4 * EMB * EMB;                     // [512][256]
    int* deg     = (int*)(WzT + VOCABSZ * EMB);             // N
    int* incl    = deg + N_NODES;                           // N
    int* bsum    = incl + N_NODES;                          // 256
    int* row_ptr = bsum + 256;                              // N+1
    int* cursor  = row_ptr + N_NODES + 1;                   // N
    int* eidx    = cursor + N_NODES;                        // E
    float* logits = (float*)PG;                             // N*512 f32 (reuses P/G)

    const int gN = (N_NODES + 127) / 128;                   // 391
    const int nb1 = (N_NODES + 255) / 256;                  // 196

    // ---- CSR build (edges constant across layers)
    hipMemsetAsync(deg, 0, N_NODES * sizeof(int), stream);
    hist_kernel<<<(E_EDGES + 255) / 256, 256, 0, stream>>>(ei, deg);
    scan1_kernel<<<nb1, 256, 0, stream>>>(deg, incl, bsum);
    scan2_kernel<<<1, 256, 0, stream>>>(bsum, nb1);
    scan3_kernel<<<nb1, 256, 0, stream>>>(deg, incl, bsum, row_ptr, cursor);
    fill_kernel<<<(E_EDGES + 255) / 256, 256, 0, stream>>>(ei, et, cursor, eidx);

    // ---- weight prep (tiny)
    convert_kernel<<<(M_SRC * HIDN / 4 + 255) / 256, 256, 0, stream>>>(x, x_b, M_SRC * HIDN);
    transpose_kernel<float><<<dim3(EMB / 32, HIDN / 32), 256, 0, stream>>>(Wsrc1, WsT1, HIDN, EMB);
    transpose_kernel<float><<<dim3(EMB / 32, HIDN / 32), 256, 0, stream>>>(Wsrc3, WsT3, HIDN, EMB);
    transpose_kernel<float><<<dim3(EMB / 32, EMB / 32), 256, 0, stream>>>(Wh1, WhT1, EMB, EMB);
    transpose_kernel<float><<<dim3(EMB / 32, EMB / 32), 256, 0, stream>>>(Wh3, WhT3, EMB, EMB);
    for (int t = 0; t < 4; t++) {
        transpose_kernel<float><<<dim3(EMB / 32, EMB / 32), 256, 0, stream>>>(
            Wrel1 + (size_t)t * EMB * EMB, WrT1 + (size_t)t * EMB * EMB, EMB, EMB);
        transpose_kernel<float><<<dim3(EMB / 32, EMB / 32), 256, 0, stream>>>(
            Wrel3 + (size_t)t * EMB * EMB, WrT3 + (size_t)t * EMB * EMB, EMB, EMB);
    }
    transpose_kernel<float><<<dim3(VOCABSZ / 32, EMB / 32), 256, 0, stream>>>(Wz, WzT, EMB, VOCABSZ);

    // ---- k = x @ Wsrc (bf16) and kT
    mgemm<0><<<dim3(M_SRC / 128, EMB / 128), 256, 0, stream>>>(x_b, WsT1, k1b, nullptr, nullptr, M_SRC, HIDN, EMB);
    mgemm<0><<<dim3(M_SRC / 128, EMB / 128), 256, 0, stream>>>(x_b, WsT3, k3b, nullptr, nullptr, M_SRC, HIDN, EMB);
    transpose_kernel<short><<<dim3(EMB / 32, M_SRC / 32), 256, 0, stream>>>(k1b, k1T, M_SRC, EMB);
    transpose_kernel<short><<<dim3(EMB / 32, M_SRC / 32), 256, 0, stream>>>(k3b, k3T, M_SRC, EMB);

    // ---- embedding
    embed_kernel<<<N_NODES, 256, 0, stream>>>(tgt_x, table, h_a);

    short* h_cur = h_a;
    short* h_nxt = h_b;
    for (int layer = 0; layer < 3; layer++) {
        const short* kb  = (layer < 2) ? k1b  : k3b;
        const short* kT  = (layer < 2) ? k1T  : k3T;
        const short* WrT = (layer < 2) ? WrT1 : WrT3;
        const short* WhT = (layer < 2) ? WhT1 : WhT3;

        // P = exp(h @ k^T / 16)  [N,1024] bf16
        mgemm<1><<<dim3(gN, M_SRC / 128), 256, 0, stream>>>(h_cur, kb, PG, nullptr, nullptr,
                                                            N_NODES, EMB, M_SRC);
        rowsum_kernel<<<N_NODES, 256, 0, stream>>>(PG, inv);
        // C = (P @ k) * inv
        mgemm<2><<<dim3(gN, EMB / 128), 256, 0, stream>>>(PG, kT, C, inv, nullptr,
                                                          N_NODES, M_SRC, EMB);
        // G = h @ [Wrel_0..3]  -> [N][1024], col block t
        mgemm<0><<<dim3(gN, 8), 256, 0, stream>>>(h_cur, WrT, PG, nullptr, nullptr,
                                                  N_NODES, EMB, 4 * EMB);
        // C[tgt] += G[src][type]
        agg_kernel<<<(N_NODES + 3) / 4, 256, 0, stream>>>(row_ptr, eidx, PG, C);
        // h_nxt = relu(h @ Wh + C)
        mgemm<3><<<dim3(gN, EMB / 128), 256, 0, stream>>>(h_cur, WhT, h_nxt, C, nullptr,
                                                          N_NODES, EMB, EMB);
        short* tmp = h_cur; h_cur = h_nxt; h_nxt = tmp;
    }

    // ---- node head
    mgemm<4><<<dim3(gN, VOCABSZ / 128), 256, 0, stream>>>(h_cur, WzT, logits, nullptr, bz,
                                                          N_NODES, EMB, VOCABSZ);
    lsm512_kernel<<<N_NODES, 256, 0, stream>>>(logits, out);

    // ---- edge head
    edge_head_kernel<<<E_EDGES / 4, 256, 0, stream>>>(ei, h_cur, Wg, bg, out + (size_t)N_NODES * VOCABSZ);
}

// Round 4
// 1101.103 us; speedup vs baseline: 20.4206x; 1.1198x over previous
//
#include <hip/hip_runtime.h>
#include <hip/hip_bf16.h>
#include <cstdint>

#define N_NODES 50000
#define M_SRC   1024
#define E_EDGES 200000
#define EMB     256
#define HIDN    512
#define VOCABSZ 512

typedef __attribute__((ext_vector_type(8))) short bf16x8;
typedef __attribute__((ext_vector_type(4))) float f32x4;

__device__ inline short f2b(float f) {
    __hip_bfloat16 b = __float2bfloat16(f);
    return *reinterpret_cast<short*>(&b);
}
__device__ inline float b2f(short s) {
    __hip_bfloat16 b = *reinterpret_cast<__hip_bfloat16*>(&s);
    return __bfloat162float(b);
}

// ---------------------------------------------------------------- embedding -> bf16
__global__ void embed_kernel(const int* __restrict__ tgt_x,
                             const float* __restrict__ table,
                             short* __restrict__ h)
{
    int n = blockIdx.x, d = threadIdx.x;
    const int* tx = tgt_x + (size_t)n * 3;
    float s = table[(size_t)tx[0] * EMB + d]
            + table[(size_t)tx[1] * EMB + d]
            + table[(size_t)tx[2] * EMB + d];
    h[(size_t)n * EMB + d] = f2b(s);
}

// ---------------------------------------------------------------- fp32 -> bf16 flat convert
__global__ void convert_kernel(const float* __restrict__ in, short* __restrict__ out, int n)
{
    int i = blockIdx.x * 256 + threadIdx.x;
    if (i * 4 < n) {
        float4 v = *(const float4*)&in[i * 4];
        short4 o;
        o.x = f2b(v.x); o.y = f2b(v.y); o.z = f2b(v.z); o.w = f2b(v.w);
        *(short4*)&out[i * 4] = o;
    }
}

// ---------------------------------------------------------------- transpose to bf16
template<typename TIN>
__global__ void transpose_kernel(const TIN* __restrict__ in, short* __restrict__ out, int R, int C)
{
    __shared__ float t[32][33];
    int tx = threadIdx.x & 31, ty = threadIdx.x >> 5;   // 32 x 8
    int r0 = blockIdx.y * 32, c0 = blockIdx.x * 32;
#pragma unroll
    for (int i = 0; i < 4; i++) {
        int r = ty + i * 8;
        TIN v = in[(size_t)(r0 + r) * C + c0 + tx];
        if constexpr (sizeof(TIN) == 4) t[r][tx] = v;
        else                            t[r][tx] = b2f(v);
    }
    __syncthreads();
#pragma unroll
    for (int i = 0; i < 4; i++) {
        int r = ty + i * 8;
        out[(size_t)(c0 + r) * R + r0 + tx] = f2b(t[tx][r]);
    }
}

// ---------------------------------------------------------------- MFMA GEMM
// out[n][j] = op( sum_k A[n][k] * BT[j][k] )
// MODE 0: bf16(acc)   MODE 3: bf16(relu(acc+aux[n*J+j]))   MODE 4: f32 acc+bias[j]
template<int MODE>
__global__ __launch_bounds__(256) void mgemm(
    const short* __restrict__ A, const short* __restrict__ BT,
    void* __restrict__ outp, const float* __restrict__ aux,
    const float* __restrict__ bias, int NR, int K, int J)
{
    __shared__ short As[128 * 40];
    __shared__ short Bs[128 * 40];
    const int tid  = threadIdx.x;
    const int n0   = blockIdx.x * 128;
    const int j0   = blockIdx.y * 128;
    const int lane = tid & 63, wid = tid >> 6;
    const int wr   = wid >> 1, wc = wid & 1;

    f32x4 acc[4][4];
#pragma unroll
    for (int m = 0; m < 4; m++)
#pragma unroll
        for (int n = 0; n < 4; n++) acc[m][n] = (f32x4){0.f, 0.f, 0.f, 0.f};

    for (int kt = 0; kt < K; kt += 32) {
#pragma unroll
        for (int r = 0; r < 2; r++) {
            int idx = tid + r * 256;
            int row = idx >> 2, ko = (idx & 3) * 8;
            int n = n0 + row;
            bf16x8 av = {0, 0, 0, 0, 0, 0, 0, 0};
            if (n < NR) av = *(const bf16x8*)&A[(size_t)n * K + kt + ko];
            *(bf16x8*)&As[row * 40 + ko] = av;
            *(bf16x8*)&Bs[row * 40 + ko] = *(const bf16x8*)&BT[(size_t)(j0 + row) * K + kt + ko];
        }
        __syncthreads();
        bf16x8 af[4], bfr[4];
#pragma unroll
        for (int m = 0; m < 4; m++)
            af[m] = *(const bf16x8*)&As[(wr * 64 + m * 16 + (lane & 15)) * 40 + (lane >> 4) * 8];
#pragma unroll
        for (int n = 0; n < 4; n++)
            bfr[n] = *(const bf16x8*)&Bs[(wc * 64 + n * 16 + (lane & 15)) * 40 + (lane >> 4) * 8];
#pragma unroll
        for (int m = 0; m < 4; m++)
#pragma unroll
            for (int n = 0; n < 4; n++)
                acc[m][n] = __builtin_amdgcn_mfma_f32_16x16x32_bf16(af[m], bfr[n], acc[m][n], 0, 0, 0);
        __syncthreads();
    }

#pragma unroll
    for (int m = 0; m < 4; m++) {
        int rbase = wr * 64 + m * 16 + ((lane >> 4) * 4);
#pragma unroll
        for (int r = 0; r < 4; r++) {
            int n_g = n0 + rbase + r;
            if (n_g >= NR) continue;
#pragma unroll
            for (int nn = 0; nn < 4; nn++) {
                int j_g = j0 + wc * 64 + nn * 16 + (lane & 15);
                float v = acc[m][nn][r];
                if constexpr (MODE == 0) {
                    ((short*)outp)[(size_t)n_g * J + j_g] = f2b(v);
                } else if constexpr (MODE == 3) {
                    float a = aux[(size_t)n_g * J + j_g];
                    ((short*)outp)[(size_t)n_g * J + j_g] = f2b(fmaxf(v + a, 0.f));
                } else {
                    ((float*)outp)[(size_t)n_g * J + j_g] = v + bias[j_g];
                }
            }
        }
    }
}

// ---------------------------------------------------------------- fused flash attention
// C[n][d] = softmax_keys(h[n]·k/16) @ k   — no-max one-pass (scores tiny).
// Per block: 64 h-rows; loop 32 chunks of 32 keys.
// S^T = k_chunk @ h^T (MFMA, swapped operands) -> exp -> P[row][key] in LDS
// O^T += kT_chunk @ P^T (MFMA).  4 waves: S n-split by rows, PV m-split by dims.
__global__ __launch_bounds__(256) void attn_flash(
    const short* __restrict__ h, const short* __restrict__ kb,
    const short* __restrict__ kT, float* __restrict__ C, int NR)
{
    __shared__ short hs[64 * 256];    // [row][dim]  XOR swizzled
    __shared__ short ks[32 * 256];    // [key][dim]  XOR swizzled
    __shared__ short kts[256 * 40];   // [dim][key]  pad-40
    __shared__ short Ps[64 * 40];     // [row][key]  pad-40
    __shared__ float linv[64];

    const int tid = threadIdx.x;
    const int lane = tid & 63, wv = tid >> 6;
    const int l4 = lane >> 4, l15 = lane & 15;
    const int n0 = blockIdx.x * 64;

    // stage h tile (once): 64x256 = 2048 bf16x8
#pragma unroll
    for (int i = 0; i < 8; i++) {
        int idx = tid + i * 256;
        int row = idx >> 5, kg = idx & 31;
        bf16x8 v = {0, 0, 0, 0, 0, 0, 0, 0};
        if (n0 + row < NR) v = *(const bf16x8*)&h[(size_t)(n0 + row) * 256 + kg * 8];
        *(bf16x8*)&hs[(row * 256 + kg * 8) ^ ((row & 7) << 3)] = v;
    }

    f32x4 oacc[4][4];
#pragma unroll
    for (int m = 0; m < 4; m++)
#pragma unroll
        for (int n = 0; n < 4; n++) oacc[m][n] = (f32x4){0.f, 0.f, 0.f, 0.f};
    float lsum = 0.f;
    const int hrow = wv * 16 + l15;

    for (int c = 0; c < 32; c++) {
        const int kt0 = c * 32;
        // stage ks [32][256]
#pragma unroll
        for (int i = 0; i < 4; i++) {
            int idx = tid + i * 256;
            int row = idx >> 5, kg = idx & 31;
            *(bf16x8*)&ks[(row * 256 + kg * 8) ^ ((row & 7) << 3)] =
                *(const bf16x8*)&kb[(size_t)(kt0 + row) * 256 + kg * 8];
        }
        // stage kts [256][32]
#pragma unroll
        for (int i = 0; i < 4; i++) {
            int idx = tid + i * 256;
            int row = idx >> 2, kg = idx & 3;
            *(bf16x8*)&kts[row * 40 + kg * 8] =
                *(const bf16x8*)&kT[(size_t)row * 1024 + kt0 + kg * 8];
        }
        __syncthreads();

        // S^T chunk: [32 keys] x [16 rows of this wave]
        f32x4 sacc[2];
        sacc[0] = (f32x4){0.f, 0.f, 0.f, 0.f};
        sacc[1] = (f32x4){0.f, 0.f, 0.f, 0.f};
#pragma unroll
        for (int kst = 0; kst < 8; kst++) {
            bf16x8 bfh = *(const bf16x8*)&hs[(hrow * 256 + kst * 32 + l4 * 8) ^ ((hrow & 7) << 3)];
#pragma unroll
            for (int m = 0; m < 2; m++) {
                int krow = m * 16 + l15;
                bf16x8 afk = *(const bf16x8*)&ks[(krow * 256 + kst * 32 + l4 * 8) ^ ((krow & 7) << 3)];
                sacc[m] = __builtin_amdgcn_mfma_f32_16x16x32_bf16(afk, bfh, sacc[m], 0, 0, 0);
            }
        }
        // exp, P write, rowsum.  frag: col(l15)=hrow, row(l4*4+r)=key
        float psum = 0.f;
#pragma unroll
        for (int m = 0; m < 2; m++) {
            float p0 = __expf(sacc[m][0] * 0.0625f);
            float p1 = __expf(sacc[m][1] * 0.0625f);
            float p2 = __expf(sacc[m][2] * 0.0625f);
            float p3 = __expf(sacc[m][3] * 0.0625f);
            psum += (p0 + p1) + (p2 + p3);
            short4 pk;
            pk.x = f2b(p0); pk.y = f2b(p1); pk.z = f2b(p2); pk.w = f2b(p3);
            *(short4*)&Ps[hrow * 40 + m * 16 + l4 * 4] = pk;
        }
        psum += __shfl_xor(psum, 16);
        psum += __shfl_xor(psum, 32);
        lsum += psum;
        __syncthreads();

        // PV: O^T[dim][row] += kT_chunk @ P^T,  wave handles dims wv*64..+63
        bf16x8 bf2[4];
#pragma unroll
        for (int n = 0; n < 4; n++)
            bf2[n] = *(const bf16x8*)&Ps[(n * 16 + l15) * 40 + l4 * 8];
#pragma unroll
        for (int mm = 0; mm < 4; mm++) {
            bf16x8 af2 = *(const bf16x8*)&kts[(wv * 64 + mm * 16 + l15) * 40 + l4 * 8];
#pragma unroll
            for (int n = 0; n < 4; n++)
                oacc[mm][n] = __builtin_amdgcn_mfma_f32_16x16x32_bf16(af2, bf2[n], oacc[mm][n], 0, 0, 0);
        }
        __syncthreads();
    }

    if (l4 == 0) linv[wv * 16 + l15] = 1.0f / lsum;
    __syncthreads();
#pragma unroll
    for (int n = 0; n < 4; n++) {
        float li = linv[n * 16 + l15];
        int hr = n0 + n * 16 + l15;
        if (hr >= NR) continue;
#pragma unroll
        for (int mm = 0; mm < 4; mm++) {
            float4 v;
            v.x = oacc[mm][n][0] * li;
            v.y = oacc[mm][n][1] * li;
            v.z = oacc[mm][n][2] * li;
            v.w = oacc[mm][n][3] * li;
            *(float4*)&C[(size_t)hr * 256 + wv * 64 + mm * 16 + l4 * 4] = v;
        }
    }
}

// ---------------------------------------------------------------- CSR build (once per call)
__global__ void hist_kernel(const int* __restrict__ ei, int* __restrict__ deg)
{
    int e = blockIdx.x * 256 + threadIdx.x;
    if (e < E_EDGES) atomicAdd(&deg[ei[E_EDGES + e]], 1);
}

__global__ void scan1_kernel(const int* __restrict__ deg, int* __restrict__ incl,
                             int* __restrict__ bsum)
{
    __shared__ int s[256];
    int i = blockIdx.x * 256 + threadIdx.x;
    int v = (i < N_NODES) ? deg[i] : 0;
    s[threadIdx.x] = v;
    __syncthreads();
#pragma unroll
    for (int off = 1; off < 256; off <<= 1) {
        int t = (threadIdx.x >= off) ? s[threadIdx.x - off] : 0;
        __syncthreads();
        s[threadIdx.x] += t;
        __syncthreads();
    }
    if (i < N_NODES) incl[i] = s[threadIdx.x];
    if (threadIdx.x == 255) bsum[blockIdx.x] = s[255];
}

__global__ void scan2_kernel(int* __restrict__ bsum, int nb)
{
    __shared__ int s[256];
    int v = (threadIdx.x < nb) ? bsum[threadIdx.x] : 0;
    s[threadIdx.x] = v;
    __syncthreads();
#pragma unroll
    for (int off = 1; off < 256; off <<= 1) {
        int t = (threadIdx.x >= off) ? s[threadIdx.x - off] : 0;
        __syncthreads();
        s[threadIdx.x] += t;
        __syncthreads();
    }
    if (threadIdx.x < nb) bsum[threadIdx.x] = s[threadIdx.x];
}

__global__ void scan3_kernel(const int* __restrict__ deg, const int* __restrict__ incl,
                             const int* __restrict__ bsum, int* __restrict__ row_ptr,
                             int* __restrict__ cursor)
{
    int i = blockIdx.x * 256 + threadIdx.x;
    if (i >= N_NODES) return;
    int pref = (blockIdx.x > 0) ? bsum[blockIdx.x - 1] : 0;
    int start = pref + incl[i] - deg[i];
    row_ptr[i] = start;
    cursor[i]  = start;
    if (i == N_NODES - 1) row_ptr[N_NODES] = pref + incl[i];
}

__global__ void fill_kernel(const int* __restrict__ ei, const int* __restrict__ et,
                            int* __restrict__ cursor, int* __restrict__ eidx)
{
    int e = blockIdx.x * 256 + threadIdx.x;
    if (e >= E_EDGES) return;
    int tg = ei[E_EDGES + e];
    int slot = atomicAdd(&cursor[tg], 1);
    eidx[slot] = ei[e] | (et[e] << 16);   // src < 65536, type < 4
}

// ---------------------------------------------------------------- CSR gather-aggregate
__global__ void agg_kernel(const int* __restrict__ row_ptr, const int* __restrict__ eidx,
                           const short* __restrict__ G, float* __restrict__ C)
{
    int w = (blockIdx.x * 256 + threadIdx.x) >> 6;
    if (w >= N_NODES) return;
    int lane = threadIdx.x & 63;
    int s0 = row_ptr[w], s1 = row_ptr[w + 1];
    float a0 = 0.f, a1 = 0.f, a2 = 0.f, a3 = 0.f;
    for (int i = s0; i < s1; i++) {
        int p = eidx[i];
        int s = p & 0xFFFF, t = p >> 16;
        short4 g = *(const short4*)&G[(size_t)s * 1024 + t * 256 + lane * 4];
        a0 += b2f(g.x); a1 += b2f(g.y); a2 += b2f(g.z); a3 += b2f(g.w);
    }
    float4 c = *(float4*)&C[(size_t)w * EMB + lane * 4];
    c.x += a0; c.y += a1; c.z += a2; c.w += a3;
    *(float4*)&C[(size_t)w * EMB + lane * 4] = c;
}

// ---------------------------------------------------------------- node log-softmax (512)
__global__ void lsm512_kernel(const float* __restrict__ logits, float* __restrict__ out)
{
    int n = blockIdx.x, tid = threadIdx.x;
    float v0 = logits[(size_t)n * VOCABSZ + tid];
    float v1 = logits[(size_t)n * VOCABSZ + 256 + tid];
    float m = fmaxf(v0, v1);
#pragma unroll
    for (int off = 32; off; off >>= 1) m = fmaxf(m, __shfl_xor(m, off));
    __shared__ float red[4], red2[4];
    int w = tid >> 6, lane = tid & 63;
    if (lane == 0) red[w] = m;
    __syncthreads();
    m = fmaxf(fmaxf(red[0], red[1]), fmaxf(red[2], red[3]));
    float e = __expf(v0 - m) + __expf(v1 - m);
#pragma unroll
    for (int off = 32; off; off >>= 1) e += __shfl_xor(e, off);
    if (lane == 0) red2[w] = e;
    __syncthreads();
    float lg = m + __logf(red2[0] + red2[1] + red2[2] + red2[3]);
    out[(size_t)n * VOCABSZ + tid] = v0 - lg;
    out[(size_t)n * VOCABSZ + 256 + tid] = v1 - lg;
}

// ---------------------------------------------------------------- edge head (weights in regs)
__global__ __launch_bounds__(256) void edge_head_kernel(
    const int* __restrict__ ei, const short* __restrict__ h,
    const float* __restrict__ Wg, const float* __restrict__ bg,
    float* __restrict__ out)
{
    int lane = threadIdx.x & 63;
    int gw   = (blockIdx.x * 256 + threadIdx.x) >> 6;
    int nw   = (gridDim.x * 256) >> 6;
    // each lane always uses Wg rows lane*4..+3 (src half) and 256+lane*4..+3 (tgt half)
    float ws[4][5], wt[4][5];
#pragma unroll
    for (int c = 0; c < 4; c++)
#pragma unroll
        for (int j = 0; j < 5; j++) {
            ws[c][j] = Wg[(size_t)(lane * 4 + c) * 5 + j];
            wt[c][j] = Wg[(size_t)(256 + lane * 4 + c) * 5 + j];
        }
    float b0 = bg[0], b1 = bg[1], b2 = bg[2], b3 = bg[3], b4 = bg[4];

    for (int e = gw; e < E_EDGES; e += nw) {
        int s = ei[e], t = ei[E_EDGES + e];
        short4 hv_s = *(const short4*)&h[(size_t)s * EMB + lane * 4];
        short4 hv_t = *(const short4*)&h[(size_t)t * EMB + lane * 4];
        float fs[4] = { b2f(hv_s.x), b2f(hv_s.y), b2f(hv_s.z), b2f(hv_s.w) };
        float ft[4] = { b2f(hv_t.x), b2f(hv_t.y), b2f(hv_t.z), b2f(hv_t.w) };
        float a0 = 0.f, a1 = 0.f, a2 = 0.f, a3 = 0.f, a4 = 0.f;
#pragma unroll
        for (int c = 0; c < 4; c++) {
            a0 += fs[c] * ws[c][0] + ft[c] * wt[c][0];
            a1 += fs[c] * ws[c][1] + ft[c] * wt[c][1];
            a2 += fs[c] * ws[c][2] + ft[c] * wt[c][2];
            a3 += fs[c] * ws[c][3] + ft[c] * wt[c][3];
            a4 += fs[c] * ws[c][4] + ft[c] * wt[c][4];
        }
#pragma unroll
        for (int off = 32; off; off >>= 1) {
            a0 += __shfl_xor(a0, off); a1 += __shfl_xor(a1, off); a2 += __shfl_xor(a2, off);
            a3 += __shfl_xor(a3, off); a4 += __shfl_xor(a4, off);
        }
        if (lane == 0) {
            float z0 = a0 + b0, z1 = a1 + b1, z2 = a2 + b2, z3 = a3 + b3, z4 = a4 + b4;
            float mm = fmaxf(fmaxf(fmaxf(z0, z1), fmaxf(z2, z3)), z4);
            float ss = __expf(z0 - mm) + __expf(z1 - mm) + __expf(z2 - mm)
                     + __expf(z3 - mm) + __expf(z4 - mm);
            float lg = mm + __logf(ss);
            float* o = &out[(size_t)e * 5];
            o[0] = z0 - lg; o[1] = z1 - lg; o[2] = z2 - lg; o[3] = z3 - lg; o[4] = z4 - lg;
        }
    }
}

// ---------------------------------------------------------------- launch
extern "C" void kernel_launch(void* const* d_in, const int* in_sizes, int n_in,
                              void* d_out, int out_size, void* d_ws, size_t ws_size,
                              hipStream_t stream)
{
    const int*   tgt_x = (const int*)  d_in[0];
    const float* x     = (const float*)d_in[1];
    const int*   ei    = (const int*)  d_in[2];
    const int*   et    = (const int*)  d_in[3];
    const float* table = (const float*)d_in[4];
    const float* Wh1   = (const float*)d_in[5];
    const float* Wrel1 = (const float*)d_in[6];
    const float* Wsrc1 = (const float*)d_in[7];
    const float* Wh3   = (const float*)d_in[8];
    const float* Wrel3 = (const float*)d_in[9];
    const float* Wsrc3 = (const float*)d_in[10];
    const float* Wz    = (const float*)d_in[11];
    const float* bz    = (const float*)d_in[12];
    const float* Wg    = (const float*)d_in[13];
    const float* bg    = (const float*)d_in[14];
    float* out = (float*)d_out;

    // ---- workspace layout
    short* h_a = (short*)d_ws;                              // N*256 bf16
    short* h_b = h_a + (size_t)N_NODES * EMB;
    float* C   = (float*)(h_b + (size_t)N_NODES * EMB);     // N*256 f32
    short* PG  = (short*)(C + (size_t)N_NODES * EMB);       // N*1024 bf16 (G; logits f32 alias)
    float* inv = (float*)(PG + (size_t)N_NODES * 1024);     // N f32 (unused now)
    short* k1b = (short*)(inv + N_NODES);                   // [1024][256]
    short* k3b = k1b + M_SRC * EMB;
    short* k1T = k3b + M_SRC * EMB;                         // [256][1024]
    short* k3T = k1T + M_SRC * EMB;
    short* x_b = k3T + M_SRC * EMB;                         // [1024][512]
    short* WsT1 = x_b + M_SRC * HIDN;                       // [256][512]
    short* WsT3 = WsT1 + EMB * HIDN;
    short* WhT1 = WsT3 + EMB * HIDN;                        // [256][256]
    short* WhT3 = WhT1 + EMB * EMB;
    short* WrT1 = WhT3 + EMB * EMB;                         // 4 x [256][256]
    short* WrT3 = WrT1 + 4 * EMB * EMB;
    short* WzT  = WrT3 + 4 * EMB * EMB;                     // [512][256]
    int* deg     = (int*)(WzT + VOCABSZ * EMB);             // N
    int* incl    = deg + N_NODES;                           // N
    int* bsum    = incl + N_NODES;                          // 256
    int* row_ptr = bsum + 256;                              // N+1
    int* cursor  = row_ptr + N_NODES + 1;                   // N
    int* eidx    = cursor + N_NODES;                        // E
    float* logits = (float*)PG;                             // N*512 f32

    const int gN = (N_NODES + 127) / 128;                   // 391
    const int gN64 = (N_NODES + 63) / 64;                   // 782
    const int nb1 = (N_NODES + 255) / 256;                  // 196

    // ---- CSR build (edges constant across layers)
    hipMemsetAsync(deg, 0, N_NODES * sizeof(int), stream);
    hist_kernel<<<(E_EDGES + 255) / 256, 256, 0, stream>>>(ei, deg);
    scan1_kernel<<<nb1, 256, 0, stream>>>(deg, incl, bsum);
    scan2_kernel<<<1, 256, 0, stream>>>(bsum, nb1);
    scan3_kernel<<<nb1, 256, 0, stream>>>(deg, incl, bsum, row_ptr, cursor);
    fill_kernel<<<(E_EDGES + 255) / 256, 256, 0, stream>>>(ei, et, cursor, eidx);

    // ---- weight prep (tiny)
    convert_kernel<<<(M_SRC * HIDN / 4 + 255) / 256, 256, 0, stream>>>(x, x_b, M_SRC * HIDN);
    transpose_kernel<float><<<dim3(EMB / 32, HIDN / 32), 256, 0, stream>>>(Wsrc1, WsT1, HIDN, EMB);
    transpose_kernel<float><<<dim3(EMB / 32, HIDN / 32), 256, 0, stream>>>(Wsrc3, WsT3, HIDN, EMB);
    transpose_kernel<float><<<dim3(EMB / 32, EMB / 32), 256, 0, stream>>>(Wh1, WhT1, EMB, EMB);
    transpose_kernel<float><<<dim3(EMB / 32, EMB / 32), 256, 0, stream>>>(Wh3, WhT3, EMB, EMB);
    for (int t = 0; t < 4; t++) {
        transpose_kernel<float><<<dim3(EMB / 32, EMB / 32), 256, 0, stream>>>(
            Wrel1 + (size_t)t * EMB * EMB, WrT1 + (size_t)t * EMB * EMB, EMB, EMB);
        transpose_kernel<float><<<dim3(EMB / 32, EMB / 32), 256, 0, stream>>>(
            Wrel3 + (size_t)t * EMB * EMB, WrT3 + (size_t)t * EMB * EMB, EMB, EMB);
    }
    transpose_kernel<float><<<dim3(VOCABSZ / 32, EMB / 32), 256, 0, stream>>>(Wz, WzT, EMB, VOCABSZ);

    // ---- k = x @ Wsrc (bf16) and kT
    mgemm<0><<<dim3(M_SRC / 128, EMB / 128), 256, 0, stream>>>(x_b, WsT1, k1b, nullptr, nullptr, M_SRC, HIDN, EMB);
    mgemm<0><<<dim3(M_SRC / 128, EMB / 128), 256, 0, stream>>>(x_b, WsT3, k3b, nullptr, nullptr, M_SRC, HIDN, EMB);
    transpose_kernel<short><<<dim3(EMB / 32, M_SRC / 32), 256, 0, stream>>>(k1b, k1T, M_SRC, EMB);
    transpose_kernel<short><<<dim3(EMB / 32, M_SRC / 32), 256, 0, stream>>>(k3b, k3T, M_SRC, EMB);

    // ---- embedding
    embed_kernel<<<N_NODES, 256, 0, stream>>>(tgt_x, table, h_a);

    short* h_cur = h_a;
    short* h_nxt = h_b;
    for (int layer = 0; layer < 3; layer++) {
        const short* kb  = (layer < 2) ? k1b  : k3b;
        const short* kT  = (layer < 2) ? k1T  : k3T;
        const short* WrT = (layer < 2) ? WrT1 : WrT3;
        const short* WhT = (layer < 2) ? WhT1 : WhT3;

        // C = softmax(h k^T / 16) @ k   (fused flash)
        attn_flash<<<gN64, 256, 0, stream>>>(h_cur, kb, kT, C, N_NODES);
        // G = h @ [Wrel_0..3]  -> [N][1024]
        mgemm<0><<<dim3(gN, 8), 256, 0, stream>>>(h_cur, WrT, PG, nullptr, nullptr,
                                                  N_NODES, EMB, 4 * EMB);
        // C[tgt] += G[src][type]
        agg_kernel<<<(N_NODES + 3) / 4, 256, 0, stream>>>(row_ptr, eidx, PG, C);
        // h_nxt = relu(h @ Wh + C)
        mgemm<3><<<dim3(gN, EMB / 128), 256, 0, stream>>>(h_cur, WhT, h_nxt, C, nullptr,
                                                          N_NODES, EMB, EMB);
        short* tmp = h_cur; h_cur = h_nxt; h_nxt = tmp;
    }

    // ---- node head
    mgemm<4><<<dim3(gN, VOCABSZ / 128), 256, 0, stream>>>(h_cur, WzT, logits, nullptr, bz,
                                                          N_NODES, EMB, VOCABSZ);
    lsm512_kernel<<<N_NODES, 256, 0, stream>>>(logits, out);

    // ---- edge head
    edge_head_kernel<<<768, 256, 0, stream>>>(ei, h_cur, Wg, bg, out + (size_t)N_NODES * VOCABSZ);
}